// Round 1
// baseline (1027.979 us; speedup 1.0000x reference)
//
#include <hip/hip_runtime.h>
#include <hip/hip_bf16.h>
#include <math.h>

#define NB 4096      // number of graphs (B)
#define DD 128       // channels
#define TT 3         // processing steps

// ---------------------------------------------------------------------------
// Transpose weight [R][C] -> [C][R] (output-coalesced)
__global__ void transpose_w(const float* __restrict__ w, float* __restrict__ wt,
                            int R, int C) {
    int idx = blockIdx.x * blockDim.x + threadIdx.x;
    if (idx >= R * C) return;
    int r = idx % R;
    int c = idx / R;
    wt[idx] = w[r * C + c];   // idx == c*R + r
}

// ---------------------------------------------------------------------------
// Segment start offsets from sorted batch array. seg[b] = first i with batch[i]>=b.
__global__ void seg_starts(const int* __restrict__ batch, int* __restrict__ seg,
                           int N, int B) {
    int i = blockIdx.x * blockDim.x + threadIdx.x;
    if (i >= N) return;
    int bi = batch[i];
    int bp = (i == 0) ? -1 : batch[i - 1];
    for (int b = bp + 1; b <= bi; ++b) seg[b] = i;
    if (i == N - 1) {
        for (int b = bi + 1; b <= B; ++b) seg[b] = N;
    }
}

// ---------------------------------------------------------------------------
// GRU cell: h' = GRUCell(q_star, h). One block handles 16 graphs, 256 threads.
// Thread t: j = t&127 (unit), gh = t>>7 selects 8-graph half.
// Weights pre-transposed: wt_ih[k][row] (k<256, row<384), wt_hh[k][row] (k<128).
__global__ __launch_bounds__(256) void gru_kernel(
    const float* qstar_in, const float* h_in,
    const float* __restrict__ wt_ih, const float* __restrict__ wt_hh,
    const float* __restrict__ b_ih, const float* __restrict__ b_hh,
    float* h_out, float* qstar_out /* writes first half (q=h') */) {

    __shared__ float qs[16 * 256];   // 16KB
    __shared__ float hs[16 * 128];   // 8KB

    const int tid = threadIdx.x;
    const int b0  = blockIdx.x * 16;

    // stage inputs (contiguous spans)
    const float* qsrc = qstar_in + (size_t)b0 * 256;
    for (int t = tid; t < 16 * 256; t += 256) qs[t] = qsrc[t];
    const float* hsrc = h_in + (size_t)b0 * 128;
    for (int t = tid; t < 16 * 128; t += 256) hs[t] = hsrc[t];
    __syncthreads();

    const int j  = tid & 127;
    const int gb = (tid >> 7) * 8;   // 0 or 8

    float air[8], aiz[8], ain[8], ahr[8], ahz[8], ahn[8];
    const float br = b_ih[j], bz = b_ih[128 + j], bn = b_ih[256 + j];
    const float cr = b_hh[j], cz = b_hh[128 + j], cn = b_hh[256 + j];
#pragma unroll
    for (int g = 0; g < 8; ++g) {
        air[g] = br; aiz[g] = bz; ain[g] = bn;
        ahr[g] = cr; ahz[g] = cz; ahn[g] = cn;
    }

    // gi = q_star @ w_ih^T   (k over 2D=256)
#pragma unroll 4
    for (int k = 0; k < 256; ++k) {
        const float wr = wt_ih[k * 384 + j];
        const float wz = wt_ih[k * 384 + 128 + j];
        const float wn = wt_ih[k * 384 + 256 + j];
#pragma unroll
        for (int g = 0; g < 8; ++g) {
            const float qv = qs[(gb + g) * 256 + k];
            air[g] = fmaf(qv, wr, air[g]);
            aiz[g] = fmaf(qv, wz, aiz[g]);
            ain[g] = fmaf(qv, wn, ain[g]);
        }
    }
    // gh = h @ w_hh^T   (k over D=128)
#pragma unroll 4
    for (int k = 0; k < 128; ++k) {
        const float wr = wt_hh[k * 384 + j];
        const float wz = wt_hh[k * 384 + 128 + j];
        const float wn = wt_hh[k * 384 + 256 + j];
#pragma unroll
        for (int g = 0; g < 8; ++g) {
            const float hv = hs[(gb + g) * 128 + k];
            ahr[g] = fmaf(hv, wr, ahr[g]);
            ahz[g] = fmaf(hv, wz, ahz[g]);
            ahn[g] = fmaf(hv, wn, ahn[g]);
        }
    }

#pragma unroll
    for (int g = 0; g < 8; ++g) {
        const int gg = gb + g;
        const float r = 1.f / (1.f + __expf(-(air[g] + ahr[g])));
        const float z = 1.f / (1.f + __expf(-(aiz[g] + ahz[g])));
        const float n = tanhf(ain[g] + r * ahn[g]);
        const float hv = hs[gg * 128 + j];
        const float hnew = (1.f - z) * n + z * hv;
        const size_t row = (size_t)(b0 + gg);
        h_out[row * 128 + j]     = hnew;
        qstar_out[row * 256 + j] = hnew;   // q half of q_star
    }
}

// ---------------------------------------------------------------------------
// Fused attention pool with ONLINE softmax: one block per graph, 8 groups of
// 32 lanes; each group streams nodes, keeps running (max, sum, acc[128]) in
// registers; groups combined in LDS. Writes r_pool into q_star second half.
__global__ __launch_bounds__(256) void attn_pool(
    const float* __restrict__ x, const float* __restrict__ h,
    const int* __restrict__ seg, float* qstar) {

    const int b   = blockIdx.x;
    const int tid = threadIdx.x;
    const int l   = tid & 31;
    const int grp = tid >> 5;

    __shared__ float  m_s[8];
    __shared__ float  s_s[8];
    __shared__ float4 acc_s[8][32];

    const int s0 = seg[b];
    const int s1 = seg[b + 1];

    if (s0 >= s1) {  // empty graph -> r_pool = 0
        if (tid < 32) {
            float4 z4 = make_float4(0.f, 0.f, 0.f, 0.f);
            *(float4*)&qstar[(size_t)b * 256 + 128 + 4 * tid] = z4;
        }
        return;
    }

    const float4 qv = *(const float4*)&h[(size_t)b * 128 + 4 * l];

    float  m = -INFINITY;
    float  s = 0.f;
    float4 acc = make_float4(0.f, 0.f, 0.f, 0.f);

    for (int n = s0 + grp; n < s1; n += 8) {
        const float4 xv = *(const float4*)&x[(size_t)n * 128 + 4 * l];
        float d = xv.x * qv.x + xv.y * qv.y + xv.z * qv.z + xv.w * qv.w;
        d += __shfl_xor(d, 1);
        d += __shfl_xor(d, 2);
        d += __shfl_xor(d, 4);
        d += __shfl_xor(d, 8);
        d += __shfl_xor(d, 16);   // all 32 lanes now hold the full dot

        if (d <= m) {
            const float w = __expf(d - m);
            s += w;
            acc.x = fmaf(w, xv.x, acc.x);
            acc.y = fmaf(w, xv.y, acc.y);
            acc.z = fmaf(w, xv.z, acc.z);
            acc.w = fmaf(w, xv.w, acc.w);
        } else {
            const float c = __expf(m - d);   // first iter: exp(-inf)=0
            s = fmaf(s, c, 1.f);
            acc.x = fmaf(acc.x, c, xv.x);
            acc.y = fmaf(acc.y, c, xv.y);
            acc.z = fmaf(acc.z, c, xv.z);
            acc.w = fmaf(acc.w, c, xv.w);
            m = d;
        }
    }

    if (l == 0) { m_s[grp] = m; s_s[grp] = s; }
    __syncthreads();

    float M = m_s[0];
#pragma unroll
    for (int g = 1; g < 8; ++g) M = fmaxf(M, m_s[g]);
    float stot = 0.f;
#pragma unroll
    for (int g = 0; g < 8; ++g) stot += s_s[g] * __expf(m_s[g] - M);

    const float f = __expf(m - M);   // empty group: exp(-inf - finite) = 0
    acc.x *= f; acc.y *= f; acc.z *= f; acc.w *= f;
    acc_s[grp][l] = acc;
    __syncthreads();

    if (tid < 32) {
        float4 r = acc_s[0][tid];
#pragma unroll
        for (int g = 1; g < 8; ++g) {
            const float4 t4 = acc_s[g][tid];
            r.x += t4.x; r.y += t4.y; r.z += t4.z; r.w += t4.w;
        }
        const float inv = 1.f / (stot + 1e-16f);
        r.x *= inv; r.y *= inv; r.z *= inv; r.w *= inv;
        *(float4*)&qstar[(size_t)b * 256 + 128 + 4 * tid] = r;
    }
}

// ---------------------------------------------------------------------------
extern "C" void kernel_launch(void* const* d_in, const int* in_sizes, int n_in,
                              void* d_out, int out_size, void* d_ws, size_t ws_size,
                              hipStream_t stream) {
    const float* x     = (const float*)d_in[0];
    const int*   batch = (const int*)d_in[1];
    const float* w_ih  = (const float*)d_in[2];
    const float* w_hh  = (const float*)d_in[3];
    const float* b_ih  = (const float*)d_in[4];
    const float* b_hh  = (const float*)d_in[5];
    const int N = in_sizes[1];

    float* qstar = (float*)d_ws;                   // NB*256
    float* h     = qstar + (size_t)NB * 256;       // NB*128
    float* wt_ih = h + (size_t)NB * 128;           // 256*384
    float* wt_hh = wt_ih + 256 * 384;              // 128*384
    int*   seg   = (int*)(wt_hh + 128 * 384);      // NB+1

    // zero q_star and h (contiguous)
    hipMemsetAsync(qstar, 0, (size_t)(NB * 256 + NB * 128) * sizeof(float), stream);

    transpose_w<<<(384 * 256 + 255) / 256, 256, 0, stream>>>(w_ih, wt_ih, 384, 256);
    transpose_w<<<(384 * 128 + 255) / 256, 256, 0, stream>>>(w_hh, wt_hh, 384, 128);
    seg_starts<<<(N + 255) / 256, 256, 0, stream>>>(batch, seg, N, NB);

    for (int t = 0; t < TT; ++t) {
        gru_kernel<<<NB / 16, 256, 0, stream>>>(qstar, h, wt_ih, wt_hh, b_ih, b_hh,
                                                h, qstar);
        attn_pool<<<NB, 256, 0, stream>>>(x, h, seg, qstar);
    }

    hipMemcpyAsync(d_out, qstar, (size_t)NB * 256 * sizeof(float),
                   hipMemcpyDeviceToDevice, stream);
}

// Round 3
// 1022.774 us; speedup vs baseline: 1.0051x; 1.0051x over previous
//
#include <hip/hip_runtime.h>
#include <hip/hip_bf16.h>
#include <math.h>

#define NB 4096      // number of graphs (B)
#define DD 128       // channels
#define TT 3         // processing steps

// ---------------------------------------------------------------------------
// Transpose weight [R][C] -> [C][R] (output-coalesced)
__global__ void transpose_w(const float* __restrict__ w, float* __restrict__ wt,
                            int R, int C) {
    int idx = blockIdx.x * blockDim.x + threadIdx.x;
    if (idx >= R * C) return;
    int r = idx % R;
    int c = idx / R;
    wt[idx] = w[r * C + c];   // idx == c*R + r
}

// ---------------------------------------------------------------------------
// Segment start offsets from sorted batch array. seg[b] = first i with batch[i]>=b.
__global__ void seg_starts(const int* __restrict__ batch, int* __restrict__ seg,
                           int N, int B) {
    int i = blockIdx.x * blockDim.x + threadIdx.x;
    if (i >= N) return;
    int bi = batch[i];
    int bp = (i == 0) ? -1 : batch[i - 1];
    for (int b = bp + 1; b <= bi; ++b) seg[b] = i;
    if (i == N - 1) {
        for (int b = bi + 1; b <= B; ++b) seg[b] = N;
    }
}

// ---------------------------------------------------------------------------
// GRU cell: h' = GRUCell(q_star, h). One block handles 16 graphs, 256 threads.
__global__ __launch_bounds__(256) void gru_kernel(
    const float* qstar_in, const float* h_in,
    const float* __restrict__ wt_ih, const float* __restrict__ wt_hh,
    const float* __restrict__ b_ih, const float* __restrict__ b_hh,
    float* h_out, float* qstar_out /* writes first half (q=h') */) {

    __shared__ float qs[16 * 256];   // 16KB
    __shared__ float hs[16 * 128];   // 8KB

    const int tid = threadIdx.x;
    const int b0  = blockIdx.x * 16;

    const float* qsrc = qstar_in + (size_t)b0 * 256;
    for (int t = tid; t < 16 * 256; t += 256) qs[t] = qsrc[t];
    const float* hsrc = h_in + (size_t)b0 * 128;
    for (int t = tid; t < 16 * 128; t += 256) hs[t] = hsrc[t];
    __syncthreads();

    const int j  = tid & 127;
    const int gb = (tid >> 7) * 8;   // 0 or 8

    float air[8], aiz[8], ain[8], ahr[8], ahz[8], ahn[8];
    const float br = b_ih[j], bz = b_ih[128 + j], bn = b_ih[256 + j];
    const float cr = b_hh[j], cz = b_hh[128 + j], cn = b_hh[256 + j];
#pragma unroll
    for (int g = 0; g < 8; ++g) {
        air[g] = br; aiz[g] = bz; ain[g] = bn;
        ahr[g] = cr; ahz[g] = cz; ahn[g] = cn;
    }

#pragma unroll 4
    for (int k = 0; k < 256; ++k) {
        const float wr = wt_ih[k * 384 + j];
        const float wz = wt_ih[k * 384 + 128 + j];
        const float wn = wt_ih[k * 384 + 256 + j];
#pragma unroll
        for (int g = 0; g < 8; ++g) {
            const float qv = qs[(gb + g) * 256 + k];
            air[g] = fmaf(qv, wr, air[g]);
            aiz[g] = fmaf(qv, wz, aiz[g]);
            ain[g] = fmaf(qv, wn, ain[g]);
        }
    }
#pragma unroll 4
    for (int k = 0; k < 128; ++k) {
        const float wr = wt_hh[k * 384 + j];
        const float wz = wt_hh[k * 384 + 128 + j];
        const float wn = wt_hh[k * 384 + 256 + j];
#pragma unroll
        for (int g = 0; g < 8; ++g) {
            const float hv = hs[(gb + g) * 128 + k];
            ahr[g] = fmaf(hv, wr, ahr[g]);
            ahz[g] = fmaf(hv, wz, ahz[g]);
            ahn[g] = fmaf(hv, wn, ahn[g]);
        }
    }

#pragma unroll
    for (int g = 0; g < 8; ++g) {
        const int gg = gb + g;
        const float r = 1.f / (1.f + __expf(-(air[g] + ahr[g])));
        const float z = 1.f / (1.f + __expf(-(aiz[g] + ahz[g])));
        const float n = tanhf(ain[g] + r * ahn[g]);
        const float hv = hs[gg * 128 + j];
        const float hnew = (1.f - z) * n + z * hv;
        const size_t row = (size_t)(b0 + gg);
        h_out[row * 128 + j]     = hnew;
        qstar_out[row * 256 + j] = hnew;
    }
}

// ---------------------------------------------------------------------------
// Attention pool v2: one block per graph, 256 threads = 32 groups of 8 lanes.
// Each group owns one node per iteration (stride 32). Each lane loads 4
// independent float4 (channels [16p,16p+16)) -> 4x MLP; shfl-reduce over 8
// lanes (3 shfls); BRANCH-FREE online softmax so the compiler can pipeline.
__global__ __launch_bounds__(256) void attn_pool(
    const float* __restrict__ x, const float* __restrict__ h,
    const int* __restrict__ seg, float* __restrict__ qstar) {

    const int b   = blockIdx.x;
    const int tid = threadIdx.x;
    const int p   = tid & 7;    // channel sub-block: channels [16p, 16p+16)
    const int g   = tid >> 3;   // group 0..31

    __shared__ float m_s[32];
    __shared__ float s_s[32];
    __shared__ float acc_s[32][128];   // 16 KB

    const int s0 = seg[b];
    const int s1 = seg[b + 1];

    if (s0 >= s1) {  // empty graph -> r_pool = 0
        if (tid < 32) {
            *(float4*)&qstar[(size_t)b * 256 + 128 + 4 * tid] =
                make_float4(0.f, 0.f, 0.f, 0.f);
        }
        return;
    }

    const float* hb = h + (size_t)b * 128 + p * 16;
    const float4 q0 = *(const float4*)(hb + 0);
    const float4 q1 = *(const float4*)(hb + 4);
    const float4 q2 = *(const float4*)(hb + 8);
    const float4 q3 = *(const float4*)(hb + 12);

    float m = -INFINITY, s = 0.f;
    float4 a0 = make_float4(0,0,0,0), a1 = a0, a2 = a0, a3 = a0;

    int n = s0 + g;
    float4 c0, c1, c2, c3;
    if (n < s1) {
        const float* xb = x + (size_t)n * 128 + p * 16;
        c0 = *(const float4*)(xb + 0);
        c1 = *(const float4*)(xb + 4);
        c2 = *(const float4*)(xb + 8);
        c3 = *(const float4*)(xb + 12);
    }

    while (n < s1) {
        const float4 d0 = c0, d1 = c1, d2 = c2, d3 = c3;
        const int n2 = n + 32;
        if (n2 < s1) {   // prefetch next node for this group
            const float* xb = x + (size_t)n2 * 128 + p * 16;
            c0 = *(const float4*)(xb + 0);
            c1 = *(const float4*)(xb + 4);
            c2 = *(const float4*)(xb + 8);
            c3 = *(const float4*)(xb + 12);
        }

        float d = d0.x*q0.x + d0.y*q0.y + d0.z*q0.z + d0.w*q0.w
                + d1.x*q1.x + d1.y*q1.y + d1.z*q1.z + d1.w*q1.w
                + d2.x*q2.x + d2.y*q2.y + d2.z*q2.z + d2.w*q2.w
                + d3.x*q3.x + d3.y*q3.y + d3.z*q3.z + d3.w*q3.w;
        d += __shfl_xor(d, 1);
        d += __shfl_xor(d, 2);
        d += __shfl_xor(d, 4);   // all 8 lanes of the group hold the dot

        const float nm = fmaxf(m, d);
        const float cs = __expf(m - nm);   // 1.0 when max unchanged; 0 on first iter
        const float w  = __expf(d - nm);
        s = fmaf(s, cs, w);
        a0.x = fmaf(a0.x, cs, w * d0.x); a0.y = fmaf(a0.y, cs, w * d0.y);
        a0.z = fmaf(a0.z, cs, w * d0.z); a0.w = fmaf(a0.w, cs, w * d0.w);
        a1.x = fmaf(a1.x, cs, w * d1.x); a1.y = fmaf(a1.y, cs, w * d1.y);
        a1.z = fmaf(a1.z, cs, w * d1.z); a1.w = fmaf(a1.w, cs, w * d1.w);
        a2.x = fmaf(a2.x, cs, w * d2.x); a2.y = fmaf(a2.y, cs, w * d2.y);
        a2.z = fmaf(a2.z, cs, w * d2.z); a2.w = fmaf(a2.w, cs, w * d2.w);
        a3.x = fmaf(a3.x, cs, w * d3.x); a3.y = fmaf(a3.y, cs, w * d3.y);
        a3.z = fmaf(a3.z, cs, w * d3.z); a3.w = fmaf(a3.w, cs, w * d3.w);
        m = nm;
        n = n2;
    }

    if (p == 0) { m_s[g] = m; s_s[g] = s; }
    __syncthreads();

    float M = m_s[0];
#pragma unroll
    for (int i = 1; i < 32; ++i) M = fmaxf(M, m_s[i]);
    float S = 0.f;
#pragma unroll
    for (int i = 0; i < 32; ++i) S += s_s[i] * __expf(m_s[i] - M);

    // empty group: m = -inf -> f = 0, acc = 0.
    const float f = __expf(m - M) / (S + 1e-16f);
    a0.x *= f; a0.y *= f; a0.z *= f; a0.w *= f;
    a1.x *= f; a1.y *= f; a1.z *= f; a1.w *= f;
    a2.x *= f; a2.y *= f; a2.z *= f; a2.w *= f;
    a3.x *= f; a3.y *= f; a3.z *= f; a3.w *= f;

    float* row = &acc_s[g][p * 16];
    *(float4*)(row + 0)  = a0;
    *(float4*)(row + 4)  = a1;
    *(float4*)(row + 8)  = a2;
    *(float4*)(row + 12) = a3;
    __syncthreads();

    if (tid < 128) {
        float r = 0.f;
#pragma unroll
        for (int gg = 0; gg < 32; ++gg) r += acc_s[gg][tid];
        qstar[(size_t)b * 256 + 128 + tid] = r;
    }
}

// ---------------------------------------------------------------------------
extern "C" void kernel_launch(void* const* d_in, const int* in_sizes, int n_in,
                              void* d_out, int out_size, void* d_ws, size_t ws_size,
                              hipStream_t stream) {
    const float* x     = (const float*)d_in[0];
    const int*   batch = (const int*)d_in[1];
    const float* w_ih  = (const float*)d_in[2];
    const float* w_hh  = (const float*)d_in[3];
    const float* b_ih  = (const float*)d_in[4];
    const float* b_hh  = (const float*)d_in[5];
    const int N = in_sizes[1];

    float* qstar = (float*)d_ws;                   // NB*256
    float* h     = qstar + (size_t)NB * 256;       // NB*128
    float* wt_ih = h + (size_t)NB * 128;           // 256*384
    float* wt_hh = wt_ih + 256 * 384;              // 128*384
    int*   seg   = (int*)(wt_hh + 128 * 384);      // NB+1

    hipMemsetAsync(qstar, 0, (size_t)(NB * 256 + NB * 128) * sizeof(float), stream);

    transpose_w<<<(384 * 256 + 255) / 256, 256, 0, stream>>>(w_ih, wt_ih, 384, 256);
    transpose_w<<<(384 * 128 + 255) / 256, 256, 0, stream>>>(w_hh, wt_hh, 384, 128);
    seg_starts<<<(N + 255) / 256, 256, 0, stream>>>(batch, seg, N, NB);

    for (int t = 0; t < TT; ++t) {
        gru_kernel<<<NB / 16, 256, 0, stream>>>(qstar, h, wt_ih, wt_hh, b_ih, b_hh,
                                                h, qstar);
        attn_pool<<<NB, 256, 0, stream>>>(x, h, seg, qstar);
    }

    hipMemcpyAsync(d_out, qstar, (size_t)NB * 256 * sizeof(float),
                   hipMemcpyDeviceToDevice, stream);
}

// Round 8
// 1021.942 us; speedup vs baseline: 1.0059x; 1.0008x over previous
//
#include <hip/hip_runtime.h>
#include <hip/hip_bf16.h>
#include <math.h>

#define NB 4096      // number of graphs (B)
#define DD 128       // channels
#define TT 3         // processing steps

// ---------------------------------------------------------------------------
// Transpose weight [R][C] -> [C][R] (output-coalesced)
__global__ void transpose_w(const float* __restrict__ w, float* __restrict__ wt,
                            int R, int C) {
    int idx = blockIdx.x * blockDim.x + threadIdx.x;
    if (idx >= R * C) return;
    int r = idx % R;
    int c = idx / R;
    wt[idx] = w[r * C + c];   // idx == c*R + r
}

// ---------------------------------------------------------------------------
// Segment start offsets from sorted batch array. seg[b] = first i with batch[i]>=b.
__global__ void seg_starts(const int* __restrict__ batch, int* __restrict__ seg,
                           int N, int B) {
    int i = blockIdx.x * blockDim.x + threadIdx.x;
    if (i >= N) return;
    int bi = batch[i];
    int bp = (i == 0) ? -1 : batch[i - 1];
    for (int b = bp + 1; b <= bi; ++b) seg[b] = i;
    if (i == N - 1) {
        for (int b = bi + 1; b <= B; ++b) seg[b] = N;
    }
}

// ---------------------------------------------------------------------------
// GRU cell: h' = GRUCell(q_star, h). One block handles 16 graphs, 256 threads.
__global__ __launch_bounds__(256) void gru_kernel(
    const float* qstar_in, const float* h_in,
    const float* __restrict__ wt_ih, const float* __restrict__ wt_hh,
    const float* __restrict__ b_ih, const float* __restrict__ b_hh,
    float* h_out, float* qstar_out /* writes first half (q=h') */) {

    __shared__ float qs[16 * 256];   // 16KB
    __shared__ float hs[16 * 128];   // 8KB

    const int tid = threadIdx.x;
    const int b0  = blockIdx.x * 16;

    const float* qsrc = qstar_in + (size_t)b0 * 256;
    for (int t = tid; t < 16 * 256; t += 256) qs[t] = qsrc[t];
    const float* hsrc = h_in + (size_t)b0 * 128;
    for (int t = tid; t < 16 * 128; t += 256) hs[t] = hsrc[t];
    __syncthreads();

    const int j  = tid & 127;
    const int gb = (tid >> 7) * 8;   // 0 or 8

    float air[8], aiz[8], ain[8], ahr[8], ahz[8], ahn[8];
    const float br = b_ih[j], bz = b_ih[128 + j], bn = b_ih[256 + j];
    const float cr = b_hh[j], cz = b_hh[128 + j], cn = b_hh[256 + j];
#pragma unroll
    for (int g = 0; g < 8; ++g) {
        air[g] = br; aiz[g] = bz; ain[g] = bn;
        ahr[g] = cr; ahz[g] = cz; ahn[g] = cn;
    }

#pragma unroll 4
    for (int k = 0; k < 256; ++k) {
        const float wr = wt_ih[k * 384 + j];
        const float wz = wt_ih[k * 384 + 128 + j];
        const float wn = wt_ih[k * 384 + 256 + j];
#pragma unroll
        for (int g = 0; g < 8; ++g) {
            const float qv = qs[(gb + g) * 256 + k];
            air[g] = fmaf(qv, wr, air[g]);
            aiz[g] = fmaf(qv, wz, aiz[g]);
            ain[g] = fmaf(qv, wn, ain[g]);
        }
    }
#pragma unroll 4
    for (int k = 0; k < 128; ++k) {
        const float wr = wt_hh[k * 384 + j];
        const float wz = wt_hh[k * 384 + 128 + j];
        const float wn = wt_hh[k * 384 + 256 + j];
#pragma unroll
        for (int g = 0; g < 8; ++g) {
            const float hv = hs[(gb + g) * 128 + k];
            ahr[g] = fmaf(hv, wr, ahr[g]);
            ahz[g] = fmaf(hv, wz, ahz[g]);
            ahn[g] = fmaf(hv, wn, ahn[g]);
        }
    }

#pragma unroll
    for (int g = 0; g < 8; ++g) {
        const int gg = gb + g;
        const float r = 1.f / (1.f + __expf(-(air[g] + ahr[g])));
        const float z = 1.f / (1.f + __expf(-(aiz[g] + ahz[g])));
        const float n = tanhf(ain[g] + r * ahn[g]);
        const float hv = hs[gg * 128 + j];
        const float hnew = (1.f - z) * n + z * hv;
        const size_t row = (size_t)(b0 + gg);
        h_out[row * 128 + j]     = hnew;
        qstar_out[row * 256 + j] = hnew;
    }
}

// ---------------------------------------------------------------------------
// Attention pool v3: one block per graph, 256 threads = 8 groups of 32 lanes.
// Each group handles 4 CONSECUTIVE nodes per iteration (2 KB contiguous per
// group, 16 KB contiguous per block window) with 4 INDEPENDENT online-softmax
// accumulators -> 4 parallel dependency chains, 4 KB in flight per wave,
// perfectly coalesced 512 B per load instruction. Branch-free masked tail
// (sentinel score -3e38, finite -1e30 init so no exp(-inf - -inf) NaN).
__global__ __launch_bounds__(256) void attn_pool(
    const float* __restrict__ x, const float* __restrict__ h,
    const int* __restrict__ seg, float* __restrict__ qstar) {

    const int b   = blockIdx.x;
    const int tid = threadIdx.x;
    const int l   = tid & 31;
    const int g   = tid >> 5;    // group 0..7

    __shared__ float  m_s[8];
    __shared__ float  s_s[8];
    __shared__ float4 acc_s[8][32];   // 4 KB

    const int s0 = seg[b];
    const int s1 = seg[b + 1];

    if (s0 >= s1) {  // empty graph -> r_pool = 0
        if (tid < 32) {
            *(float4*)&qstar[(size_t)b * 256 + 128 + 4 * tid] =
                make_float4(0.f, 0.f, 0.f, 0.f);
        }
        return;
    }

    const float4 qv = *(const float4*)&h[(size_t)b * 128 + 4 * l];
    const int len = s1 - s0;
    const int nt  = (len + 31) >> 5;   // block window = 32 nodes/iter, uniform

    float m0 = -1e30f, m1 = -1e30f, m2 = -1e30f, m3 = -1e30f;
    float sA = 0.f, sB = 0.f, sC = 0.f, sD = 0.f;
    float4 a0 = make_float4(0,0,0,0), a1 = a0, a2 = a0, a3 = a0;

    int base = s0 + g * 4;             // this group's 4-node slot in the window
    const int last = s1 - 1;

    float4 c0, c1, c2, c3;
    {   // prefetch iteration 0 (clamped)
        c0 = *(const float4*)&x[(size_t)min(base + 0, last) * 128 + 4 * l];
        c1 = *(const float4*)&x[(size_t)min(base + 1, last) * 128 + 4 * l];
        c2 = *(const float4*)&x[(size_t)min(base + 2, last) * 128 + 4 * l];
        c3 = *(const float4*)&x[(size_t)min(base + 3, last) * 128 + 4 * l];
    }

    for (int j = 0; j < nt; ++j) {
        const float4 d0 = c0, d1 = c1, d2 = c2, d3 = c3;
        const int nb = base + 32;
        if (j + 1 < nt) {   // prefetch next window (clamped)
            c0 = *(const float4*)&x[(size_t)min(nb + 0, last) * 128 + 4 * l];
            c1 = *(const float4*)&x[(size_t)min(nb + 1, last) * 128 + 4 * l];
            c2 = *(const float4*)&x[(size_t)min(nb + 2, last) * 128 + 4 * l];
            c3 = *(const float4*)&x[(size_t)min(nb + 3, last) * 128 + 4 * l];
        }

        float e0 = d0.x*qv.x + d0.y*qv.y + d0.z*qv.z + d0.w*qv.w;
        float e1 = d1.x*qv.x + d1.y*qv.y + d1.z*qv.z + d1.w*qv.w;
        float e2 = d2.x*qv.x + d2.y*qv.y + d2.z*qv.z + d2.w*qv.w;
        float e3 = d3.x*qv.x + d3.y*qv.y + d3.z*qv.z + d3.w*qv.w;
#pragma unroll
        for (int o = 1; o < 32; o <<= 1) {   // 4 interleaved shfl-reduce chains
            e0 += __shfl_xor(e0, o);
            e1 += __shfl_xor(e1, o);
            e2 += __shfl_xor(e2, o);
            e3 += __shfl_xor(e3, o);
        }
        // mask tail nodes (uniform within group -> no lane divergence)
        e0 = (base + 0 < s1) ? e0 : -3e38f;
        e1 = (base + 1 < s1) ? e1 : -3e38f;
        e2 = (base + 2 < s1) ? e2 : -3e38f;
        e3 = (base + 3 < s1) ? e3 : -3e38f;

        // 4 independent branch-free online updates
        {
            const float nm = fmaxf(m0, e0);
            const float cs = __expf(m0 - nm), w = __expf(e0 - nm);
            sA = fmaf(sA, cs, w);
            a0.x = fmaf(a0.x, cs, w * d0.x); a0.y = fmaf(a0.y, cs, w * d0.y);
            a0.z = fmaf(a0.z, cs, w * d0.z); a0.w = fmaf(a0.w, cs, w * d0.w);
            m0 = nm;
        }
        {
            const float nm = fmaxf(m1, e1);
            const float cs = __expf(m1 - nm), w = __expf(e1 - nm);
            sB = fmaf(sB, cs, w);
            a1.x = fmaf(a1.x, cs, w * d1.x); a1.y = fmaf(a1.y, cs, w * d1.y);
            a1.z = fmaf(a1.z, cs, w * d1.z); a1.w = fmaf(a1.w, cs, w * d1.w);
            m1 = nm;
        }
        {
            const float nm = fmaxf(m2, e2);
            const float cs = __expf(m2 - nm), w = __expf(e2 - nm);
            sC = fmaf(sC, cs, w);
            a2.x = fmaf(a2.x, cs, w * d2.x); a2.y = fmaf(a2.y, cs, w * d2.y);
            a2.z = fmaf(a2.z, cs, w * d2.z); a2.w = fmaf(a2.w, cs, w * d2.w);
            m2 = nm;
        }
        {
            const float nm = fmaxf(m3, e3);
            const float cs = __expf(m3 - nm), w = __expf(e3 - nm);
            sD = fmaf(sD, cs, w);
            a3.x = fmaf(a3.x, cs, w * d3.x); a3.y = fmaf(a3.y, cs, w * d3.y);
            a3.z = fmaf(a3.z, cs, w * d3.z); a3.w = fmaf(a3.w, cs, w * d3.w);
            m3 = nm;
        }
        base = nb;
    }

    // merge 4 accumulators (per-lane, sentinel-safe: exp(-1e30 - -1e30)=exp(0))
    {
        const float M = fmaxf(m0, m1);
        const float f0 = __expf(m0 - M), f1 = __expf(m1 - M);
        sA = sA * f0 + sB * f1;
        a0.x = a0.x*f0 + a1.x*f1; a0.y = a0.y*f0 + a1.y*f1;
        a0.z = a0.z*f0 + a1.z*f1; a0.w = a0.w*f0 + a1.w*f1;
        m0 = M;
    }
    {
        const float M = fmaxf(m2, m3);
        const float f2 = __expf(m2 - M), f3 = __expf(m3 - M);
        sC = sC * f2 + sD * f3;
        a2.x = a2.x*f2 + a3.x*f3; a2.y = a2.y*f2 + a3.y*f3;
        a2.z = a2.z*f2 + a3.z*f3; a2.w = a2.w*f2 + a3.w*f3;
        m2 = M;
    }
    {
        const float M = fmaxf(m0, m2);
        const float f0 = __expf(m0 - M), f2 = __expf(m2 - M);
        sA = sA * f0 + sC * f2;
        a0.x = a0.x*f0 + a2.x*f2; a0.y = a0.y*f0 + a2.y*f2;
        a0.z = a0.z*f0 + a2.z*f2; a0.w = a0.w*f0 + a2.w*f2;
        m0 = M;
    }

    if (l == 0) { m_s[g] = m0; s_s[g] = sA; }
    __syncthreads();

    float M = m_s[0];
#pragma unroll
    for (int i = 1; i < 8; ++i) M = fmaxf(M, m_s[i]);
    float S = 0.f;
#pragma unroll
    for (int i = 0; i < 8; ++i) S += s_s[i] * __expf(m_s[i] - M);

    const float f = __expf(m0 - M) / (S + 1e-16f);   // sentinel group -> 0
    a0.x *= f; a0.y *= f; a0.z *= f; a0.w *= f;
    acc_s[g][l] = a0;
    __syncthreads();

    if (tid < 32) {
        float4 r = acc_s[0][tid];
#pragma unroll
        for (int gg = 1; gg < 8; ++gg) {
            const float4 t4 = acc_s[gg][tid];
            r.x += t4.x; r.y += t4.y; r.z += t4.z; r.w += t4.w;
        }
        *(float4*)&qstar[(size_t)b * 256 + 128 + 4 * tid] = r;
    }
}

// ---------------------------------------------------------------------------
extern "C" void kernel_launch(void* const* d_in, const int* in_sizes, int n_in,
                              void* d_out, int out_size, void* d_ws, size_t ws_size,
                              hipStream_t stream) {
    const float* x     = (const float*)d_in[0];
    const int*   batch = (const int*)d_in[1];
    const float* w_ih  = (const float*)d_in[2];
    const float* w_hh  = (const float*)d_in[3];
    const float* b_ih  = (const float*)d_in[4];
    const float* b_hh  = (const float*)d_in[5];
    const int N = in_sizes[1];

    float* qstar = (float*)d_ws;                   // NB*256
    float* h     = qstar + (size_t)NB * 256;       // NB*128
    float* wt_ih = h + (size_t)NB * 128;           // 256*384
    float* wt_hh = wt_ih + 256 * 384;              // 128*384
    int*   seg   = (int*)(wt_hh + 128 * 384);      // NB+1

    hipMemsetAsync(qstar, 0, (size_t)(NB * 256 + NB * 128) * sizeof(float), stream);

    transpose_w<<<(384 * 256 + 255) / 256, 256, 0, stream>>>(w_ih, wt_ih, 384, 256);
    transpose_w<<<(384 * 128 + 255) / 256, 256, 0, stream>>>(w_hh, wt_hh, 384, 128);
    seg_starts<<<(N + 255) / 256, 256, 0, stream>>>(batch, seg, N, NB);

    for (int t = 0; t < TT; ++t) {
        gru_kernel<<<NB / 16, 256, 0, stream>>>(qstar, h, wt_ih, wt_hh, b_ih, b_hh,
                                                h, qstar);
        attn_pool<<<NB, 256, 0, stream>>>(x, h, seg, qstar);
    }

    hipMemcpyAsync(d_out, qstar, (size_t)NB * 256 * sizeof(float),
                   hipMemcpyDeviceToDevice, stream);
}